// Round 11
// baseline (187.636 us; speedup 1.0000x reference)
//
#include <hip/hip_runtime.h>
#include <cstdint>

// ---------------- problem constants ----------------
static constexpr int B_  = 8192;
static constexpr int NW_ = 192;                 // NS + NV

typedef __attribute__((ext_vector_type(8))) _Float16 h8v;
typedef __attribute__((ext_vector_type(2))) _Float16 h2v;
typedef __attribute__((ext_vector_type(4))) float f4v;
typedef __attribute__((ext_vector_type(2))) float f2v;
typedef __attribute__((ext_vector_type(4))) unsigned u4v;
typedef __attribute__((ext_vector_type(2))) unsigned u2v;

#define DI __device__ __forceinline__

DI h2v uh(unsigned u) { return __builtin_bit_cast(h2v, u); }
DI unsigned hu(h2v h) { return __builtin_bit_cast(unsigned, h); }
DI h2v hsplat(unsigned short bits) {
  _Float16 v = __builtin_bit_cast(_Float16, bits);
  h2v t; t.x = v; t.y = v; return t;
}
DI unsigned hpack(float lo, float hi) {
  h2v t; t.x = (_Float16)lo; t.y = (_Float16)hi;
  return __builtin_bit_cast(unsigned, t);
}
DI short f2h_bits(float f) { return __builtin_bit_cast(short, (_Float16)f); }

DI f4v mfma16h(h8v a, h8v b, f4v c) {
  return __builtin_amdgcn_mfma_f32_16x16x32_f16(a, b, c, 0, 0, 0);
}

// ---- block-symmetry tables (2 bits per block index) ----
static constexpr unsigned PK_BU0 = 606436u;   // {0,1,2,3,0,0,0,1,1,2}
static constexpr unsigned PK_BV0 = 1030628u;  // {0,1,2,3,1,2,3,2,3,3}
static constexpr unsigned PK_BU2 = 4u;        // {0,1,0}
static constexpr unsigned PK_BV2 = 20u;       // {0,1,1}
DI int tab2(unsigned pack, int blk) { return (int)((pack >> (2 * blk)) & 3u); }

// ---------------- prep (coalesced): 768 blocks x 256 threads ----------------
__global__ void prep_all(const float* __restrict__ w000, const float* __restrict__ w110,
                         const float* __restrict__ w011, const float* __restrict__ w111,
                         short* __restrict__ wsc, short* __restrict__ wve) {
  __shared__ unsigned short T[32][200];
  const int t = threadIdx.x;
  const int bi = blockIdx.x;
  const float s000 = 1.0f / (128.0f * 1.41421356237f);   // (1/N0) * inv_sqrt2
  const float s110 = 1.0f / (64.0f * 2.44948974968f);    // (1/(N1*sqrt3)) * inv_sqrt2
  const float sv   = 1.0f / 128.0f;

  if (bi < 416) {
    const int s = bi;
    const float* W; int dim; float scale; int blk, ik, bu, bv;
    if (s < 320) {
      blk = s >> 5; ik = s & 31;
      bu = tab2(PK_BU0, blk); bv = tab2(PK_BV0, blk);
      W = w000; dim = 128; scale = s000;
    } else {
      int sp = s - 320; blk = sp >> 5; ik = sp & 31;
      bu = tab2(PK_BU2, blk); bv = tab2(PK_BV2, blk);
      W = w110; dim = 64; scale = s110;
    }
    const int u = bu * 32 + ik;
    const int v = t >> 3, l8 = t & 7;
    float a[24];
    const float* pA = W + ((size_t)(u * dim) + bv * 32 + v) * 192 + l8 * 24;
#pragma unroll
    for (int jj = 0; jj < 6; ++jj) {
      f4v x4 = *(const f4v*)(pA + jj * 4);
      a[jj * 4] = x4.x; a[jj * 4 + 1] = x4.y; a[jj * 4 + 2] = x4.z; a[jj * 4 + 3] = x4.w;
    }
    if (bu != bv) {
      const float* pB = W + ((size_t)((bv * 32 + v)) * dim + u) * 192 + l8 * 24;
#pragma unroll
      for (int jj = 0; jj < 6; ++jj) {
        f4v x4 = *(const f4v*)(pB + jj * 4);
        a[jj * 4] += x4.x; a[jj * 4 + 1] += x4.y; a[jj * 4 + 2] += x4.z; a[jj * 4 + 3] += x4.w;
      }
    }
    unsigned o[12];
#pragma unroll
    for (int i = 0; i < 12; ++i) o[i] = hpack(a[2 * i] * scale, a[2 * i + 1] * scale);
#pragma unroll
    for (int i = 0; i < 3; ++i)
      *(u4v*)(&T[v][l8 * 24 + i * 8]) = u4v{o[4 * i], o[4 * i + 1], o[4 * i + 2], o[4 * i + 3]};
    __syncthreads();
    short* dst = wsc + (size_t)s * 6144;
#pragma unroll
    for (int k = 0; k < 3; ++k) {
      const int unit = t * 3 + k;
      const int F = unit >> 6, lane = unit & 63;
      const int n = F * 16 + (lane & 15);
      const int vr = (lane >> 4) * 8;
      short oo[8];
#pragma unroll
      for (int j = 0; j < 8; ++j) oo[j] = (short)T[vr + j][n];
      *(h8v*)(dst + F * 512 + lane * 8) = *(h8v*)oo;
    }
  } else {
    const int s = bi - 416;
    if (s < 256) {
      const int k32 = t >> 3, l8 = t & 7;
      const float* p = w011 + ((size_t)(s * 32 + k32)) * 64 + l8 * 8;
      f4v x0_ = *(const f4v*)p, x1_ = *(const f4v*)(p + 4);
      u4v o{hpack(x0_.x * sv, x0_.y * sv), hpack(x0_.z * sv, x0_.w * sv),
            hpack(x1_.x * sv, x1_.y * sv), hpack(x1_.z * sv, x1_.w * sv)};
      *(u4v*)(&T[k32][l8 * 8]) = o;
    } else {
      const int sp = s - 256;
      const int blk = sp >> 5, ik = sp & 31;
      const int bu = tab2(PK_BU2, blk), bv = tab2(PK_BV2, blk);
      const int u = bu * 32 + ik;
      const int v = t >> 3, l8 = t & 7;
      float a[8];
      const float* pA = w111 + ((size_t)(u * 64) + bv * 32 + v) * 64 + l8 * 8;
      f4v x0_ = *(const f4v*)pA, x1_ = *(const f4v*)(pA + 4);
      a[0] = x0_.x; a[1] = x0_.y; a[2] = x0_.z; a[3] = x0_.w;
      a[4] = x1_.x; a[5] = x1_.y; a[6] = x1_.z; a[7] = x1_.w;
      if (bu != bv) {
        const float* pB = w111 + ((size_t)((bv * 32 + v)) * 64 + u) * 64 + l8 * 8;
        f4v y0 = *(const f4v*)pB, y1 = *(const f4v*)(pB + 4);
        a[0] -= y0.x; a[1] -= y0.y; a[2] -= y0.z; a[3] -= y0.w;
        a[4] -= y1.x; a[5] -= y1.y; a[6] -= y1.z; a[7] -= y1.w;
      }
      u4v o{hpack(a[0] * sv, a[1] * sv), hpack(a[2] * sv, a[3] * sv),
            hpack(a[4] * sv, a[5] * sv), hpack(a[6] * sv, a[7] * sv)};
      *(u4v*)(&T[v][l8 * 8]) = o;
    }
    __syncthreads();
    const int nf = t >> 6, lane = t & 63;
    const int n = nf * 16 + (lane & 15);
    const int vr = (lane >> 4) * 8;
    short oo[8];
#pragma unroll
    for (int j = 0; j < 8; ++j) oo[j] = (short)T[vr + j][n];
    *(h8v*)(wve + (size_t)s * 2048 + nf * 512 + lane * 8) = *(h8v*)oo;
  }
}

// ---------------- LDS staging: 32 rows of x, f16 (first 512 threads) ----------------
#define X0H_STRIDE 136
#define X1_STRIDE  200

DI void stage_x32w(const float* __restrict__ x, int b0,
                   unsigned short* X0H, unsigned short* X1) {
  const int t = threadIdx.x;            // t < 512
  const int row = t >> 4, l16 = t & 15; // 32 rows x 16 lanes
  const float* src = x + (size_t)(b0 + row) * 320;
  f4v v0 = *(const f4v*)(src + l16 * 8);
  f4v v1 = *(const f4v*)(src + l16 * 8 + 4);
  u4v o{hpack(v0.x, v0.y), hpack(v0.z, v0.w), hpack(v1.x, v1.y), hpack(v1.z, v1.w)};
  *(u4v*)(&X0H[row * X0H_STRIDE + l16 * 8]) = o;
  float buf[12];
  f4v a0 = *(const f4v*)(src + 128 + l16 * 12);
  f4v a1 = *(const f4v*)(src + 128 + l16 * 12 + 4);
  f4v a2 = *(const f4v*)(src + 128 + l16 * 12 + 8);
  buf[0] = a0.x; buf[1] = a0.y; buf[2] = a0.z; buf[3] = a0.w;
  buf[4] = a1.x; buf[5] = a1.y; buf[6] = a1.z; buf[7] = a1.w;
  buf[8] = a2.x; buf[9] = a2.y; buf[10] = a2.z; buf[11] = a2.w;
#pragma unroll
  for (int i = 0; i < 3; ++i) {
    u2v w2{hpack(buf[i], buf[3 + i]), hpack(buf[6 + i], buf[9 + i])};
    *(u2v*)(&X1[row * X1_STRIDE + i * 64 + l16 * 4]) = w2;
  }
}

DI void loadB6(h8v* dst, const short* __restrict__ p) {
#pragma unroll
  for (int nf = 0; nf < 6; ++nf) dst[nf] = *(const h8v*)(p + nf * 512);
}
DI void loadB2(h8v* dst, const short* __restrict__ p) {
  dst[0] = *(const h8v*)p;
  dst[1] = *(const h8v*)(p + 512);
}

// ---------------- mega-kernel: 16 waves/block (4 waves/SIMD) ----------------
// R11: grid 256 x 1024 threads. Waves: w0-7 sc {nh2 x kh4}, w8-15 vec {nh2 x kh4}
// -> each SIMD holds 2 sc + 2 vec waves (4 waves/SIMD, 2x the latency coverage
// of R9/R10 at IDENTICAL per-block weight traffic: 6.55 MB, duplication-free).
// Register budget: 512/4 = 128 total incl 48 acc -> arch <= 80; use the proven
// depth-1 ping-pong bodies (R4 measured 64 arch VGPR on this loop shape).
// kh4 reduce: kh3->dumpA, kh2->dumpB (parallel), kh1 folds A+=B+own, kh0 final.
__global__ __launch_bounds__(1024, 4)
void gemm_fused(const float* __restrict__ x, const short* __restrict__ wsc,
                const short* __restrict__ wve, float* __restrict__ out) {
  __shared__ unsigned short X0H[32 * X0H_STRIDE];   // 8704 B
  __shared__ unsigned short X1[32 * X1_STRIDE];     // 12800 B
  __shared__ f4v dumpA[4][12][64];                  // 49152 B
  __shared__ f4v dumpB[4][12][64];                  // 49152 B
  __shared__ float G[32][64];                       // 8192 B  (total 128000 B)
  const int b0 = blockIdx.x * 32;

  if (threadIdx.x < 512) stage_x32w(x, b0, X0H, X1);
  __syncthreads();

  const int t0 = threadIdx.x;
  const int w = t0 >> 6, lane = t0 & 63;   // w in 0..15
  const bool isvec = w >= 8;
  const int ww = w & 7;
  const int nh = ww & 1, kh = ww >> 1;     // kh in 0..3
  const int q = lane >> 4, r = lane & 15, q8 = q * 8;

  f4v acc[12];
#pragma unroll
  for (int i = 0; i < 12; ++i) acc[i] = f4v{0.f, 0.f, 0.f, 0.f};

  if (!isvec) {
    // ================= scalar path =================
    const unsigned short* x0f[2];
    const unsigned short* x1f[2];
#pragma unroll
    for (int f = 0; f < 2; ++f) {
      x0f[f] = &X0H[(f * 16 + r) * X0H_STRIDE];
      x1f[f] = &X1[(f * 16 + r) * X1_STRIDE];
    }

    // ---- region 1: x0 pair blocks, 80 steps (K-quarter kh) ----
    {
      const int s0 = kh * 80;
      const short* wp = wsc + ((size_t)s0 * 12 + nh * 6) * 512 + lane * 8;
      u4v pv[2]; pv[0] = u4v{0, 0, 0, 0}; pv[1] = u4v{0, 0, 0, 0};
      int bu32 = 0;
      h8v ba[6], bb[6];
      loadB6(ba, wp);
      auto step = [&](int t, const h8v* b) {
        const int s = s0 + t;
        const int ik = s & 31;
        if (t == 0 || ik == 0) {        // new 32x32 block (wave-uniform)
          const int blk = s >> 5;
          const int bv32 = tab2(PK_BV0, blk) * 32;
          bu32 = tab2(PK_BU0, blk) * 32;
          pv[0] = *(const u4v*)(x0f[0] + bv32 + q8);
          pv[1] = *(const u4v*)(x0f[1] + bv32 + q8);
        }
        h2v xu0 = hsplat(x0f[0][bu32 + ik]);
        h2v xu1 = hsplat(x0f[1][bu32 + ik]);
        u4v pa0, pa1;
#pragma unroll
        for (int m = 0; m < 4; ++m) {
          pa0[m] = hu(uh(pv[0][m]) * xu0);
          pa1[m] = hu(uh(pv[1][m]) * xu1);
        }
        h8v a0 = __builtin_bit_cast(h8v, pa0);
        h8v a1 = __builtin_bit_cast(h8v, pa1);
        __builtin_amdgcn_s_setprio(1);
#pragma unroll
        for (int nf = 0; nf < 6; ++nf) {
          acc[nf]     = mfma16h(a0, b[nf], acc[nf]);
          acc[6 + nf] = mfma16h(a1, b[nf], acc[6 + nf]);
        }
        __builtin_amdgcn_s_setprio(0);
      };
      for (int t2 = 0; t2 < 40; ++t2) {
        loadB6(bb, wp + 6144);
        step(2 * t2, ba);
        if (t2 != 39) loadB6(ba, wp + 12288);
        step(2 * t2 + 1, bb);
        wp += 12288;
      }
    }

    // ---- region 2: x1-dots pair blocks, 24 steps (K-quarter kh) ----
    {
      const int sp0 = kh * 24;
      const short* wp = wsc + ((size_t)(320 + sp0) * 12 + nh * 6) * 512 + lane * 8;
      h8v ba[6], bb[6];
      loadB6(ba, wp);
      auto step = [&](int t, const h8v* b) {
        const int sp = sp0 + t;
        const int blk = sp >> 5, ik = sp & 31;
        const int bu32 = tab2(PK_BU2, blk) * 32;
        const int bv32 = tab2(PK_BV2, blk) * 32;
        h8v a[2];
#pragma unroll
        for (int f = 0; f < 2; ++f) {
          h2v us0 = hsplat(x1f[f][bu32 + ik]);
          h2v us1 = hsplat(x1f[f][64 + bu32 + ik]);
          h2v us2 = hsplat(x1f[f][128 + bu32 + ik]);
          u4v p0 = *(const u4v*)(x1f[f] + bv32 + q8);
          u4v p1 = *(const u4v*)(x1f[f] + 64 + bv32 + q8);
          u4v p2 = *(const u4v*)(x1f[f] + 128 + bv32 + q8);
          u4v pa;
#pragma unroll
          for (int m = 0; m < 4; ++m) {
            h2v sm = uh(p0[m]) * us0;
            sm = sm + uh(p1[m]) * us1;
            sm = sm + uh(p2[m]) * us2;
            pa[m] = hu(sm);
          }
          a[f] = __builtin_bit_cast(h8v, pa);
        }
        __builtin_amdgcn_s_setprio(1);
#pragma unroll
        for (int nf = 0; nf < 6; ++nf) {
          acc[nf]     = mfma16h(a[0], b[nf], acc[nf]);
          acc[6 + nf] = mfma16h(a[1], b[nf], acc[6 + nf]);
        }
        __builtin_amdgcn_s_setprio(0);
      };
      for (int t2 = 0; t2 < 12; ++t2) {
        loadB6(bb, wp + 6144);
        step(2 * t2, ba);
        if (t2 != 11) loadB6(ba, wp + 12288);
        step(2 * t2 + 1, bb);
        wp += 12288;
      }
    }
  } else {
    // ================= vector path =================
    const unsigned short* x0r[2];
    const unsigned short* x1r[2];
#pragma unroll
    for (int ff = 0; ff < 2; ++ff) {
      x0r[ff] = &X0H[(ff * 16 + r) * X0H_STRIDE];
      x1r[ff] = &X1[(ff * 16 + r) * X1_STRIDE];
    }

    // ---- region 1: v011, 64 steps (u in [kh*32,+32), j in {0,1}) ----
    {
      const int u0 = kh * 32;
      const short* wp = wve + (size_t)(u0 * 2) * 2048 + nh * 1024 + lane * 8;
      h8v ba[2], bb[2];
      loadB2(ba, wp);
      auto vstep = [&](int st, const h8v* b) {
        const int g = st >> 1, j = st & 1;
        const int vb = j * 32 + q8;
        h8v a[2][3];
#pragma unroll
        for (int ff = 0; ff < 2; ++ff) {
          h2v xu2 = hsplat(x0r[ff][u0 + g]);
#pragma unroll
          for (int i = 0; i < 3; ++i) {
            u4v p = *(const u4v*)(x1r[ff] + i * 64 + vb);
            u4v pa;
#pragma unroll
            for (int m = 0; m < 4; ++m) pa[m] = hu(uh(p[m]) * xu2);
            a[ff][i] = __builtin_bit_cast(h8v, pa);
          }
        }
        __builtin_amdgcn_s_setprio(1);
#pragma unroll
        for (int ip = 0; ip < 3; ++ip)
#pragma unroll
          for (int nfl = 0; nfl < 2; ++nfl)
#pragma unroll
            for (int ff = 0; ff < 2; ++ff)
              acc[(ff * 3 + ip) * 2 + nfl] =
                  mfma16h(a[ff][ip], b[nfl], acc[(ff * 3 + ip) * 2 + nfl]);
        __builtin_amdgcn_s_setprio(0);
      };
      for (int t2 = 0; t2 < 32; ++t2) {
        loadB2(bb, wp + 2048);
        vstep(2 * t2, ba);
        if (t2 != 31) loadB2(ba, wp + 4096);
        vstep(2 * t2 + 1, bb);
        wp += 4096;
      }
    }

    // ---- region 2: v111 antisym, 24 steps (sp in [kh*24,+24)) ----
    {
      const int sp0 = kh * 24;
      const short* wp = wve + (size_t)(256 + sp0) * 2048 + nh * 1024 + lane * 8;
      h8v ba[2], bb[2];
      loadB2(ba, wp);
      auto vstep = [&](int t, const h8v* b) {
        const int sp = sp0 + t;
        const int blk = sp >> 5, ik = sp & 31;
        const int bu32 = tab2(PK_BU2, blk) * 32;
        const int bv32 = tab2(PK_BV2, blk) * 32;
        h8v a[2][3];
#pragma unroll
        for (int ff = 0; ff < 2; ++ff) {
          h2v us[3];
          u4v p[3];
#pragma unroll
          for (int i = 0; i < 3; ++i) {
            us[i] = hsplat(x1r[ff][i * 64 + bu32 + ik]);
            p[i] = *(const u4v*)(x1r[ff] + i * 64 + bv32 + q8);
          }
#pragma unroll
          for (int ip = 0; ip < 3; ++ip) {
            const int i1 = (ip + 1) % 3, i2 = (ip + 2) % 3;
            u4v pa;
#pragma unroll
            for (int m = 0; m < 4; ++m)
              pa[m] = hu(uh(p[i2][m]) * us[i1] - uh(p[i1][m]) * us[i2]);
            a[ff][ip] = __builtin_bit_cast(h8v, pa);
          }
        }
        __builtin_amdgcn_s_setprio(1);
#pragma unroll
        for (int ip = 0; ip < 3; ++ip)
#pragma unroll
          for (int nfl = 0; nfl < 2; ++nfl)
#pragma unroll
            for (int ff = 0; ff < 2; ++ff)
              acc[(ff * 3 + ip) * 2 + nfl] =
                  mfma16h(a[ff][ip], b[nfl], acc[(ff * 3 + ip) * 2 + nfl]);
        __builtin_amdgcn_s_setprio(0);
      };
      for (int t2 = 0; t2 < 12; ++t2) {
        loadB2(bb, wp + 2048);
        vstep(2 * t2, ba);
        if (t2 != 11) loadB2(ba, wp + 4096);
        vstep(2 * t2 + 1, bb);
        wp += 4096;
      }
    }
  }

  // ---- kh4 reduce (kh3->A, kh2->B parallel; kh1 folds; kh0 final) ----
  const int slot = (isvec ? 2 : 0) + nh;
  if (kh == 3) {
#pragma unroll
    for (int i = 0; i < 12; ++i) dumpA[slot][i][lane] = acc[i];
  } else if (kh == 2) {
#pragma unroll
    for (int i = 0; i < 12; ++i) dumpB[slot][i][lane] = acc[i];
  }
  __syncthreads();
  if (kh == 1) {
#pragma unroll
    for (int i = 0; i < 12; ++i)
      dumpA[slot][i][lane] = dumpA[slot][i][lane] + dumpB[slot][i][lane] + acc[i];
  }
  __syncthreads();

  if (kh == 0 && !isvec) {
    // scalar outputs: silu for n<128, sigmoid gates -> LDS for n>=128
#pragma unroll
    for (int f = 0; f < 2; ++f)
#pragma unroll
      for (int nf = 0; nf < 6; ++nf) {
        f4v v = acc[f * 6 + nf] + dumpA[slot][f * 6 + nf][lane];
        const int n = (nh * 6 + nf) * 16 + r;
#pragma unroll
        for (int reg = 0; reg < 4; ++reg) {
          const int row = f * 16 + q * 4 + reg;
          const float val = v[reg];
          const float sg = 1.0f / (1.0f + __expf(-val));
          if (n < 128) out[(size_t)(b0 + row) * 320 + n] = val * sg;
          else         G[row][n - 128] = sg;
        }
      }
  }
  __syncthreads();                       // gates ready

  if (kh == 0 && isvec) {
#pragma unroll
    for (int ff = 0; ff < 2; ++ff)
#pragma unroll
      for (int ip = 0; ip < 3; ++ip)
#pragma unroll
        for (int nfl = 0; nfl < 2; ++nfl) {
          const int ai = (ff * 3 + ip) * 2 + nfl;
          f4v v = acc[ai] + dumpA[slot][ai][lane];
          const int n = (nh * 2 + nfl) * 16 + r;
#pragma unroll
          for (int reg = 0; reg < 4; ++reg) {
            const int row = ff * 16 + q * 4 + reg;
            out[(size_t)(b0 + row) * 320 + 128 + n * 3 + ip] = v[reg] * G[row][n];
          }
        }
  }
}

// ---------------- launch ----------------
extern "C" void kernel_launch(void* const* d_in, const int* in_sizes, int n_in,
                              void* d_out, int out_size, void* d_ws, size_t ws_size,
                              hipStream_t stream) {
  const float* x    = (const float*)d_in[0];
  const float* w000 = (const float*)d_in[1];
  const float* w110 = (const float*)d_in[2];
  const float* w011 = (const float*)d_in[3];
  const float* w111 = (const float*)d_in[4];
  float* out = (float*)d_out;

  char* ws = (char*)d_ws;
  short* wsc = (short*)ws;                        // 416*6144*2 = 5,111,808 B
  short* wve = (short*)(ws + 5111808);            // 352*2048*2 = 1,441,792 B

  prep_all  <<<768, 256, 0, stream>>>(w000, w110, w011, w111, wsc, wve);
  gemm_fused<<<256, 1024, 0, stream>>>(x, wsc, wve, out);
}

// Round 12
// 184.870 us; speedup vs baseline: 1.0150x; 1.0150x over previous
//
#include <hip/hip_runtime.h>
#include <cstdint>

// ---------------- problem constants ----------------
static constexpr int B_  = 8192;
static constexpr int NW_ = 192;                 // NS + NV

typedef __attribute__((ext_vector_type(8))) _Float16 h8v;
typedef __attribute__((ext_vector_type(2))) _Float16 h2v;
typedef __attribute__((ext_vector_type(4))) float f4v;
typedef __attribute__((ext_vector_type(2))) float f2v;
typedef __attribute__((ext_vector_type(4))) unsigned u4v;
typedef __attribute__((ext_vector_type(2))) unsigned u2v;

#define DI __device__ __forceinline__

DI h2v uh(unsigned u) { return __builtin_bit_cast(h2v, u); }
DI unsigned hu(h2v h) { return __builtin_bit_cast(unsigned, h); }
DI h2v hsplat(unsigned short bits) {
  _Float16 v = __builtin_bit_cast(_Float16, bits);
  h2v t; t.x = v; t.y = v; return t;
}
DI unsigned hpack(float lo, float hi) {
  h2v t; t.x = (_Float16)lo; t.y = (_Float16)hi;
  return __builtin_bit_cast(unsigned, t);
}
DI short f2h_bits(float f) { return __builtin_bit_cast(short, (_Float16)f); }

DI f4v mfma16h(h8v a, h8v b, f4v c) {
  return __builtin_amdgcn_mfma_f32_16x16x32_f16(a, b, c, 0, 0, 0);
}

// async global->LDS: per-lane global src, wave-uniform LDS dst (+lane*16 by HW)
DI void glds16(const short* g, char* l) {
  __builtin_amdgcn_global_load_lds(
      (const __attribute__((address_space(1))) void*)g,
      (__attribute__((address_space(3))) void*)l, 16, 0, 0);
}

// ---- block-symmetry tables (2 bits per block index) ----
static constexpr unsigned PK_BU0 = 606436u;   // {0,1,2,3,0,0,0,1,1,2}
static constexpr unsigned PK_BV0 = 1030628u;  // {0,1,2,3,1,2,3,2,3,3}
static constexpr unsigned PK_BU2 = 4u;        // {0,1,0}
static constexpr unsigned PK_BV2 = 20u;       // {0,1,1}
DI int tab2(unsigned pack, int blk) { return (int)((pack >> (2 * blk)) & 3u); }

// ---------------- prep (coalesced): 768 blocks x 256 threads ----------------
__global__ void prep_all(const float* __restrict__ w000, const float* __restrict__ w110,
                         const float* __restrict__ w011, const float* __restrict__ w111,
                         short* __restrict__ wsc, short* __restrict__ wve) {
  __shared__ unsigned short T[32][200];
  const int t = threadIdx.x;
  const int bi = blockIdx.x;
  const float s000 = 1.0f / (128.0f * 1.41421356237f);   // (1/N0) * inv_sqrt2
  const float s110 = 1.0f / (64.0f * 2.44948974968f);    // (1/(N1*sqrt3)) * inv_sqrt2
  const float sv   = 1.0f / 128.0f;

  if (bi < 416) {
    const int s = bi;
    const float* W; int dim; float scale; int blk, ik, bu, bv;
    if (s < 320) {
      blk = s >> 5; ik = s & 31;
      bu = tab2(PK_BU0, blk); bv = tab2(PK_BV0, blk);
      W = w000; dim = 128; scale = s000;
    } else {
      int sp = s - 320; blk = sp >> 5; ik = sp & 31;
      bu = tab2(PK_BU2, blk); bv = tab2(PK_BV2, blk);
      W = w110; dim = 64; scale = s110;
    }
    const int u = bu * 32 + ik;
    const int v = t >> 3, l8 = t & 7;
    float a[24];
    const float* pA = W + ((size_t)(u * dim) + bv * 32 + v) * 192 + l8 * 24;
#pragma unroll
    for (int jj = 0; jj < 6; ++jj) {
      f4v x4 = *(const f4v*)(pA + jj * 4);
      a[jj * 4] = x4.x; a[jj * 4 + 1] = x4.y; a[jj * 4 + 2] = x4.z; a[jj * 4 + 3] = x4.w;
    }
    if (bu != bv) {
      const float* pB = W + ((size_t)((bv * 32 + v)) * dim + u) * 192 + l8 * 24;
#pragma unroll
      for (int jj = 0; jj < 6; ++jj) {
        f4v x4 = *(const f4v*)(pB + jj * 4);
        a[jj * 4] += x4.x; a[jj * 4 + 1] += x4.y; a[jj * 4 + 2] += x4.z; a[jj * 4 + 3] += x4.w;
      }
    }
    unsigned o[12];
#pragma unroll
    for (int i = 0; i < 12; ++i) o[i] = hpack(a[2 * i] * scale, a[2 * i + 1] * scale);
#pragma unroll
    for (int i = 0; i < 3; ++i)
      *(u4v*)(&T[v][l8 * 24 + i * 8]) = u4v{o[4 * i], o[4 * i + 1], o[4 * i + 2], o[4 * i + 3]};
    __syncthreads();
    short* dst = wsc + (size_t)s * 6144;
#pragma unroll
    for (int k = 0; k < 3; ++k) {
      const int unit = t * 3 + k;
      const int F = unit >> 6, lane = unit & 63;
      const int n = F * 16 + (lane & 15);
      const int vr = (lane >> 4) * 8;
      short oo[8];
#pragma unroll
      for (int j = 0; j < 8; ++j) oo[j] = (short)T[vr + j][n];
      *(h8v*)(dst + F * 512 + lane * 8) = *(h8v*)oo;
    }
  } else {
    const int s = bi - 416;
    if (s < 256) {
      const int k32 = t >> 3, l8 = t & 7;
      const float* p = w011 + ((size_t)(s * 32 + k32)) * 64 + l8 * 8;
      f4v x0_ = *(const f4v*)p, x1_ = *(const f4v*)(p + 4);
      u4v o{hpack(x0_.x * sv, x0_.y * sv), hpack(x0_.z * sv, x0_.w * sv),
            hpack(x1_.x * sv, x1_.y * sv), hpack(x1_.z * sv, x1_.w * sv)};
      *(u4v*)(&T[k32][l8 * 8]) = o;
    } else {
      const int sp = s - 256;
      const int blk = sp >> 5, ik = sp & 31;
      const int bu = tab2(PK_BU2, blk), bv = tab2(PK_BV2, blk);
      const int u = bu * 32 + ik;
      const int v = t >> 3, l8 = t & 7;
      float a[8];
      const float* pA = w111 + ((size_t)(u * 64) + bv * 32 + v) * 64 + l8 * 8;
      f4v x0_ = *(const f4v*)pA, x1_ = *(const f4v*)(pA + 4);
      a[0] = x0_.x; a[1] = x0_.y; a[2] = x0_.z; a[3] = x0_.w;
      a[4] = x1_.x; a[5] = x1_.y; a[6] = x1_.z; a[7] = x1_.w;
      if (bu != bv) {
        const float* pB = w111 + ((size_t)((bv * 32 + v)) * 64 + u) * 64 + l8 * 8;
        f4v y0 = *(const f4v*)pB, y1 = *(const f4v*)(pB + 4);
        a[0] -= y0.x; a[1] -= y0.y; a[2] -= y0.z; a[3] -= y0.w;
        a[4] -= y1.x; a[5] -= y1.y; a[6] -= y1.z; a[7] -= y1.w;
      }
      u4v o{hpack(a[0] * sv, a[1] * sv), hpack(a[2] * sv, a[3] * sv),
            hpack(a[4] * sv, a[5] * sv), hpack(a[6] * sv, a[7] * sv)};
      *(u4v*)(&T[v][l8 * 8]) = o;
    }
    __syncthreads();
    const int nf = t >> 6, lane = t & 63;
    const int n = nf * 16 + (lane & 15);
    const int vr = (lane >> 4) * 8;
    short oo[8];
#pragma unroll
    for (int j = 0; j < 8; ++j) oo[j] = (short)T[vr + j][n];
    *(h8v*)(wve + (size_t)s * 2048 + nf * 512 + lane * 8) = *(h8v*)oo;
  }
}

// ---------------- LDS staging: 32 rows of x, f16, 512 threads ----------------
#define X0H_STRIDE 136
#define X1_STRIDE  200

DI void stage_x32w(const float* __restrict__ x, int b0,
                   unsigned short* X0H, unsigned short* X1) {
  const int t = threadIdx.x;            // 512 threads
  const int row = t >> 4, l16 = t & 15; // 32 rows x 16 lanes
  const float* src = x + (size_t)(b0 + row) * 320;
  f4v v0 = *(const f4v*)(src + l16 * 8);
  f4v v1 = *(const f4v*)(src + l16 * 8 + 4);
  u4v o{hpack(v0.x, v0.y), hpack(v0.z, v0.w), hpack(v1.x, v1.y), hpack(v1.z, v1.w)};
  *(u4v*)(&X0H[row * X0H_STRIDE + l16 * 8]) = o;
  float buf[12];
  f4v a0 = *(const f4v*)(src + 128 + l16 * 12);
  f4v a1 = *(const f4v*)(src + 128 + l16 * 12 + 4);
  f4v a2 = *(const f4v*)(src + 128 + l16 * 12 + 8);
  buf[0] = a0.x; buf[1] = a0.y; buf[2] = a0.z; buf[3] = a0.w;
  buf[4] = a1.x; buf[5] = a1.y; buf[6] = a1.z; buf[7] = a1.w;
  buf[8] = a2.x; buf[9] = a2.y; buf[10] = a2.z; buf[11] = a2.w;
#pragma unroll
  for (int i = 0; i < 3; ++i) {
    u2v w2{hpack(buf[i], buf[3 + i]), hpack(buf[6 + i], buf[9 + i])};
    *(u2v*)(&X1[row * X1_STRIDE + i * 64 + l16 * 4]) = w2;
  }
}

DI void loadB6(h8v* dst, const short* __restrict__ p) {
#pragma unroll
  for (int nf = 0; nf < 6; ++nf) dst[nf] = *(const h8v*)(p + nf * 512);
}
DI void loadB2(h8v* dst, const short* __restrict__ p) {
  dst[0] = *(const h8v*)p;
  dst[1] = *(const h8v*)(p + 512);
}
// issue 6 async frag copies (one step) into a wave-private LDS slot
DI void stageB6(const short* wp, char* slot) {
#pragma unroll
  for (int nf = 0; nf < 6; ++nf) glds16(wp + nf * 512, slot + nf * 1024);
}
// read 6 frags (one step) from an LDS slot into registers
DI void readB6(h8v* dst, const char* slot, int lane) {
#pragma unroll
  for (int nf = 0; nf < 6; ++nf)
    dst[nf] = *(const h8v*)(slot + nf * 1024 + lane * 16);
}

// ---------------- mega-kernel: R9 + sc LDS-ring prefetch (depth-4) ----------------
// R12: sc region-1 B-fragments flow global->LDS (async, 5-slot/6KB per-wave ring,
// constant s_waitcnt vmcnt(18)) -> ds_read -> MFMA. Load-to-use distance ~4 steps
// (~460cy) covers L3-class misses that the 4-buffer register ring (345cy) exposed.
// R11 lesson: TLP (4 waves/SIMD, depth-1) LOST to 2 waves/SIMD x depth-3; and kh4
// widened the weight working set (FETCH 31->43MB). So: keep R9's 8-wave/kh2 shape.
// dump/G are carved (union) from the sc ring; a barrier before dump writes
// protects the alias. LDS total 144,384 B (1 block/CU).
__global__ __launch_bounds__(512, 2)
void gemm_fused(const float* __restrict__ x, const short* __restrict__ wsc,
                const short* __restrict__ wve, float* __restrict__ out) {
  __shared__ unsigned short X0H[32 * X0H_STRIDE];   // 8704 B
  __shared__ unsigned short X1[32 * X1_STRIDE];     // 12800 B
  __shared__ alignas(16) char RING[122880];         // 4 sc waves x 5 slots x 6144
  f4v (*dump)[12][64] = reinterpret_cast<f4v (*)[12][64]>(RING);      // 49152 B
  float (*G)[64] = reinterpret_cast<float (*)[64]>(RING + 49152);     // 8192 B
  const int b0 = blockIdx.x * 32;

  stage_x32w(x, b0, X0H, X1);
  __syncthreads();

  const int t0 = threadIdx.x;
  const int w = t0 >> 6, lane = t0 & 63;   // w in 0..7
  const bool isvec = w >= 4;
  const int nh = w & 1, kh = (w >> 1) & 1;
  const int q = lane >> 4, r = lane & 15, q8 = q * 8;

  f4v acc[12];
#pragma unroll
  for (int i = 0; i < 12; ++i) acc[i] = f4v{0.f, 0.f, 0.f, 0.f};

  if (!isvec) {
    // ================= scalar path =================
    const unsigned short* x0f[2];
    const unsigned short* x1f[2];
#pragma unroll
    for (int f = 0; f < 2; ++f) {
      x0f[f] = &X0H[(f * 16 + r) * X0H_STRIDE];
      x1f[f] = &X1[(f * 16 + r) * X1_STRIDE];
    }

    // ---- region 1: x0 pair blocks, 160 steps; LDS-ring depth-4 prefetch ----
    {
      const int s0 = kh * 160;
      const short* wp = wsc + ((size_t)s0 * 12 + nh * 6) * 512 + lane * 8;
      char* ring = RING + w * 30720;    // wave-private 5-slot ring
      u4v pv[2]; pv[0] = u4v{0, 0, 0, 0}; pv[1] = u4v{0, 0, 0, 0};
      int bu32 = 0;
      // prologue: stage steps 0..3 into slots 0..3, read step 0
      stageB6(wp,          ring);
      stageB6(wp + 6144,   ring + 6144);
      stageB6(wp + 12288,  ring + 12288);
      stageB6(wp + 18432,  ring + 18432);
      asm volatile("s_waitcnt vmcnt(18)" ::: "memory");
      h8v ba[6], bb[6];
      readB6(ba, ring, lane);
      int rslot = 1, wslot = 4;         // read slot for t+1; write slot for t+4
      auto step = [&](int t, const h8v* b) {
        const int s = s0 + t;
        const int ik = s & 31;
        if (t == 0 || ik == 0) {        // new 32x32 block (wave-uniform)
          const int blk = s >> 5;
          const int bv32 = tab2(PK_BV0, blk) * 32;
          bu32 = tab2(PK_BU0, blk) * 32;
          pv[0] = *(const u4v*)(x0f[0] + bv32 + q8);
          pv[1] = *(const u4v*)(x0f[1] + bv32 + q8);
        }
        h2v xu0 = hsplat(x0f[0][bu32 + ik]);
        h2v xu1 = hsplat(x0f[1][bu32 + ik]);
        u4v pa0, pa1;
#pragma unroll
        for (int m = 0; m < 4; ++m) {
          pa0[m] = hu(uh(pv[0][m]) * xu0);
          pa1[m] = hu(uh(pv[1][m]) * xu1);
        }
        h8v a0 = __builtin_bit_cast(h8v, pa0);
        h8v a1 = __builtin_bit_cast(h8v, pa1);
        __builtin_amdgcn_s_setprio(1);
#pragma unroll
        for (int nf = 0; nf < 6; ++nf) {
          acc[nf]     = mfma16h(a0, b[nf], acc[nf]);
          acc[6 + nf] = mfma16h(a1, b[nf], acc[6 + nf]);
        }
        __builtin_amdgcn_s_setprio(0);
      };
      for (int t2 = 0; t2 < 80; ++t2) {
        // even step t = 2*t2 (data in ba)
        if (t2 < 78) {                  // stage step 2*t2+4
          stageB6(wp + (size_t)(2 * t2 + 4) * 6144, ring + wslot * 6144);
          wslot = (wslot == 4) ? 0 : wslot + 1;
        }
        asm volatile("s_waitcnt vmcnt(18)" ::: "memory");
        readB6(bb, ring + rslot * 6144, lane);   // step 2*t2+1
        rslot = (rslot == 4) ? 0 : rslot + 1;
        step(2 * t2, ba);
        // odd step t = 2*t2+1 (data in bb)
        if (t2 < 78) {                  // stage step 2*t2+5
          stageB6(wp + (size_t)(2 * t2 + 5) * 6144, ring + wslot * 6144);
          wslot = (wslot == 4) ? 0 : wslot + 1;
        }
        asm volatile("s_waitcnt vmcnt(18)" ::: "memory");
        if (t2 != 79) {
          readB6(ba, ring + rslot * 6144, lane); // step 2*t2+2
          rslot = (rslot == 4) ? 0 : rslot + 1;
        }
        step(2 * t2 + 1, bb);
      }
      asm volatile("s_waitcnt vmcnt(0)" ::: "memory");  // drain before region 2
    }

    // ---- region 2: x1-dots pair blocks, 48 steps; register ring depth-3 ----
    {
      const int sp0 = kh * 48;
      const short* wp = wsc + ((size_t)(320 + sp0) * 12 + nh * 6) * 512 + lane * 8;
      h8v b[4][6];
      loadB6(b[0], wp); loadB6(b[1], wp + 6144); loadB6(b[2], wp + 12288);
      for (int t4 = 0; t4 < 12; ++t4) {
#pragma unroll
        for (int uu = 0; uu < 4; ++uu) {
          const int t = t4 * 4 + uu;
          if (t < 45) loadB6(b[(uu + 3) & 3], wp + (size_t)(t + 3) * 6144);
          const int sp = sp0 + t;
          const int blk = sp >> 5, ik = sp & 31;
          const int bu32 = tab2(PK_BU2, blk) * 32;
          const int bv32 = tab2(PK_BV2, blk) * 32;
          h8v a[2];
#pragma unroll
          for (int f = 0; f < 2; ++f) {
            h2v us0 = hsplat(x1f[f][bu32 + ik]);
            h2v us1 = hsplat(x1f[f][64 + bu32 + ik]);
            h2v us2 = hsplat(x1f[f][128 + bu32 + ik]);
            u4v p0 = *(const u4v*)(x1f[f] + bv32 + q8);
            u4v p1 = *(const u4v*)(x1f[f] + 64 + bv32 + q8);
            u4v p2 = *(const u4v*)(x1f[f] + 128 + bv32 + q8);
            u4v pa;
#pragma unroll
            for (int m = 0; m < 4; ++m) {
              h2v sm = uh(p0[m]) * us0;
              sm = sm + uh(p1[m]) * us1;
              sm = sm + uh(p2[m]) * us2;
              pa[m] = hu(sm);
            }
            a[f] = __builtin_bit_cast(h8v, pa);
          }
          __builtin_amdgcn_s_setprio(1);
#pragma unroll
          for (int nf = 0; nf < 6; ++nf) {
            acc[nf]     = mfma16h(a[0], b[uu & 3][nf], acc[nf]);
            acc[6 + nf] = mfma16h(a[1], b[uu & 3][nf], acc[6 + nf]);
          }
          __builtin_amdgcn_s_setprio(0);
        }
      }
    }
  } else {
    // ================= vector path (R9, unchanged) =================
    const unsigned short* x0r[2];
    const unsigned short* x1r[2];
#pragma unroll
    for (int ff = 0; ff < 2; ++ff) {
      x0r[ff] = &X0H[(ff * 16 + r) * X0H_STRIDE];
      x1r[ff] = &X1[(ff * 16 + r) * X1_STRIDE];
    }

    // ---- region 1: v011, 128 steps, depth-3 ----
    {
      const int u0 = kh * 64;
      const short* wp = wve + (size_t)(u0 * 2) * 2048 + nh * 1024 + lane * 8;
      h8v b[4][2];
      loadB2(b[0], wp); loadB2(b[1], wp + 2048); loadB2(b[2], wp + 4096);
      for (int t4 = 0; t4 < 32; ++t4) {
#pragma unroll
        for (int uu = 0; uu < 4; ++uu) {
          const int t = t4 * 4 + uu;
          if (t < 125) loadB2(b[(uu + 3) & 3], wp + (size_t)(t + 3) * 2048);
          const int g = t >> 1, j = t & 1;
          const int vb = j * 32 + q8;
          h8v a[2][3];
#pragma unroll
          for (int ff = 0; ff < 2; ++ff) {
            h2v xu2 = hsplat(x0r[ff][u0 + g]);
#pragma unroll
            for (int i = 0; i < 3; ++i) {
              u4v p = *(const u4v*)(x1r[ff] + i * 64 + vb);
              u4v pa;
#pragma unroll
              for (int m = 0; m < 4; ++m) pa[m] = hu(uh(p[m]) * xu2);
              a[ff][i] = __builtin_bit_cast(h8v, pa);
            }
          }
          __builtin_amdgcn_s_setprio(1);
#pragma unroll
          for (int ip = 0; ip < 3; ++ip)
#pragma unroll
            for (int nfl = 0; nfl < 2; ++nfl)
#pragma unroll
              for (int ff = 0; ff < 2; ++ff)
                acc[(ff * 3 + ip) * 2 + nfl] =
                    mfma16h(a[ff][ip], b[uu & 3][nfl], acc[(ff * 3 + ip) * 2 + nfl]);
          __builtin_amdgcn_s_setprio(0);
        }
      }
    }

    // ---- region 2: v111 antisym, 48 steps ----
    {
      const int sp0 = kh * 48;
      const short* wp = wve + (size_t)(256 + sp0) * 2048 + nh * 1024 + lane * 8;
      h8v b[4][2];
      loadB2(b[0], wp); loadB2(b[1], wp + 2048); loadB2(b[2], wp + 4096);
      for (int t4 = 0; t4 < 12; ++t4) {
#pragma unroll
        for (int uu = 0; uu < 4; ++uu) {
          const int t = t4 * 4 + uu;
          if (t < 45) loadB2(b[(uu + 3) & 3], wp + (size_t)(t + 3) * 2048);
          const int sp = sp0 + t;
          const int blk = sp >> 5, ik = sp & 31;
          const int bu32 = tab2(PK_BU2, blk) * 32;
          const int bv32 = tab2(PK_BV2, blk) * 32;
          h8v a[2][3];
#pragma unroll
          for (int ff = 0; ff < 2; ++ff) {
            h2v us[3];
            u4v p[3];
#pragma unroll
            for (int i = 0; i < 3; ++i) {
              us[i] = hsplat(x1r[ff][i * 64 + bu32 + ik]);
              p[i] = *(const u4v*)(x1r[ff] + i * 64 + bv32 + q8);
            }
#pragma unroll
            for (int ip = 0; ip < 3; ++ip) {
              const int i1 = (ip + 1) % 3, i2 = (ip + 2) % 3;
              u4v pa;
#pragma unroll
              for (int m = 0; m < 4; ++m)
                pa[m] = hu(uh(p[i2][m]) * us[i1] - uh(p[i1][m]) * us[i2]);
              a[ff][ip] = __builtin_bit_cast(h8v, pa);
            }
          }
          __builtin_amdgcn_s_setprio(1);
#pragma unroll
          for (int ip = 0; ip < 3; ++ip)
#pragma unroll
            for (int nfl = 0; nfl < 2; ++nfl)
#pragma unroll
              for (int ff = 0; ff < 2; ++ff)
                acc[(ff * 3 + ip) * 2 + nfl] =
                    mfma16h(a[ff][ip], b[uu & 3][nfl], acc[(ff * 3 + ip) * 2 + nfl]);
          __builtin_amdgcn_s_setprio(0);
        }
      }
    }
  }

  // ---- all ring use done: safe to reuse RING as dump/G ----
  __syncthreads();

  const int slot = (isvec ? 2 : 0) + nh;
  if (kh == 1) {
#pragma unroll
    for (int i = 0; i < 12; ++i) dump[slot][i][lane] = acc[i];
  }
  __syncthreads();

  if (kh == 0 && !isvec) {
    // scalar outputs: silu for n<128, sigmoid gates -> LDS for n>=128
#pragma unroll
    for (int f = 0; f < 2; ++f)
#pragma unroll
      for (int nf = 0; nf < 6; ++nf) {
        f4v v = acc[f * 6 + nf] + dump[slot][f * 6 + nf][lane];
        const int n = (nh * 6 + nf) * 16 + r;
#pragma unroll
        for (int reg = 0; reg < 4; ++reg) {
          const int row = f * 16 + q * 4 + reg;
          const float val = v[reg];
          const float sg = 1.0f / (1.0f + __expf(-val));
          if (n < 128) out[(size_t)(b0 + row) * 320 + n] = val * sg;
          else         G[row][n - 128] = sg;
        }
      }
  }
  __syncthreads();                       // gates ready

  if (kh == 0 && isvec) {
#pragma unroll
    for (int ff = 0; ff < 2; ++ff)
#pragma unroll
      for (int ip = 0; ip < 3; ++ip)
#pragma unroll
        for (int nfl = 0; nfl < 2; ++nfl) {
          const int ai = (ff * 3 + ip) * 2 + nfl;
          f4v v = acc[ai] + dump[slot][ai][lane];
          const int n = (nh * 2 + nfl) * 16 + r;
#pragma unroll
          for (int reg = 0; reg < 4; ++reg) {
            const int row = ff * 16 + q * 4 + reg;
            out[(size_t)(b0 + row) * 320 + 128 + n * 3 + ip] = v[reg] * G[row][n];
          }
        }
  }
}

// ---------------- launch ----------------
extern "C" void kernel_launch(void* const* d_in, const int* in_sizes, int n_in,
                              void* d_out, int out_size, void* d_ws, size_t ws_size,
                              hipStream_t stream) {
  const float* x    = (const float*)d_in[0];
  const float* w000 = (const float*)d_in[1];
  const float* w110 = (const float*)d_in[2];
  const float* w011 = (const float*)d_in[3];
  const float* w111 = (const float*)d_in[4];
  float* out = (float*)d_out;

  char* ws = (char*)d_ws;
  short* wsc = (short*)ws;                        // 416*6144*2 = 5,111,808 B
  short* wve = (short*)(ws + 5111808);            // 352*2048*2 = 1,441,792 B

  prep_all  <<<768, 256, 0, stream>>>(w000, w110, w011, w111, wsc, wve);
  gemm_fused<<<256, 512, 0, stream>>>(x, wsc, wve, out);
}

// Round 13
// 157.517 us; speedup vs baseline: 1.1912x; 1.1737x over previous
//
#include <hip/hip_runtime.h>
#include <cstdint>

// ---------------- problem constants ----------------
static constexpr int B_  = 8192;
static constexpr int NW_ = 192;                 // NS + NV

typedef __attribute__((ext_vector_type(8))) _Float16 h8v;
typedef __attribute__((ext_vector_type(2))) _Float16 h2v;
typedef __attribute__((ext_vector_type(4))) float f4v;
typedef __attribute__((ext_vector_type(2))) float f2v;
typedef __attribute__((ext_vector_type(4))) unsigned u4v;
typedef __attribute__((ext_vector_type(2))) unsigned u2v;

#define DI __device__ __forceinline__

DI h2v uh(unsigned u) { return __builtin_bit_cast(h2v, u); }
DI unsigned hu(h2v h) { return __builtin_bit_cast(unsigned, h); }
DI h2v hsplat(unsigned short bits) {
  _Float16 v = __builtin_bit_cast(_Float16, bits);
  h2v t; t.x = v; t.y = v; return t;
}
DI unsigned hpack(float lo, float hi) {
  h2v t; t.x = (_Float16)lo; t.y = (_Float16)hi;
  return __builtin_bit_cast(unsigned, t);
}
DI short f2h_bits(float f) { return __builtin_bit_cast(short, (_Float16)f); }

DI f4v mfma16h(h8v a, h8v b, f4v c) {
  return __builtin_amdgcn_mfma_f32_16x16x32_f16(a, b, c, 0, 0, 0);
}

// ---- block-symmetry tables (2 bits per block index) ----
static constexpr unsigned PK_BU0 = 606436u;   // {0,1,2,3,0,0,0,1,1,2}
static constexpr unsigned PK_BV0 = 1030628u;  // {0,1,2,3,1,2,3,2,3,3}
static constexpr unsigned PK_BU2 = 4u;        // {0,1,0}
static constexpr unsigned PK_BV2 = 20u;       // {0,1,1}
DI int tab2(unsigned pack, int blk) { return (int)((pack >> (2 * blk)) & 3u); }

// ---------------- prep (coalesced): 768 blocks x 256 threads ----------------
__global__ void prep_all(const float* __restrict__ w000, const float* __restrict__ w110,
                         const float* __restrict__ w011, const float* __restrict__ w111,
                         short* __restrict__ wsc, short* __restrict__ wve) {
  __shared__ unsigned short T[32][200];
  const int t = threadIdx.x;
  const int bi = blockIdx.x;
  const float s000 = 1.0f / (128.0f * 1.41421356237f);   // (1/N0) * inv_sqrt2
  const float s110 = 1.0f / (64.0f * 2.44948974968f);    // (1/(N1*sqrt3)) * inv_sqrt2
  const float sv   = 1.0f / 128.0f;

  if (bi < 416) {
    const int s = bi;
    const float* W; int dim; float scale; int blk, ik, bu, bv;
    if (s < 320) {
      blk = s >> 5; ik = s & 31;
      bu = tab2(PK_BU0, blk); bv = tab2(PK_BV0, blk);
      W = w000; dim = 128; scale = s000;
    } else {
      int sp = s - 320; blk = sp >> 5; ik = sp & 31;
      bu = tab2(PK_BU2, blk); bv = tab2(PK_BV2, blk);
      W = w110; dim = 64; scale = s110;
    }
    const int u = bu * 32 + ik;
    const int v = t >> 3, l8 = t & 7;
    float a[24];
    const float* pA = W + ((size_t)(u * dim) + bv * 32 + v) * 192 + l8 * 24;
#pragma unroll
    for (int jj = 0; jj < 6; ++jj) {
      f4v x4 = *(const f4v*)(pA + jj * 4);
      a[jj * 4] = x4.x; a[jj * 4 + 1] = x4.y; a[jj * 4 + 2] = x4.z; a[jj * 4 + 3] = x4.w;
    }
    if (bu != bv) {
      const float* pB = W + ((size_t)((bv * 32 + v)) * dim + u) * 192 + l8 * 24;
#pragma unroll
      for (int jj = 0; jj < 6; ++jj) {
        f4v x4 = *(const f4v*)(pB + jj * 4);
        a[jj * 4] += x4.x; a[jj * 4 + 1] += x4.y; a[jj * 4 + 2] += x4.z; a[jj * 4 + 3] += x4.w;
      }
    }
    unsigned o[12];
#pragma unroll
    for (int i = 0; i < 12; ++i) o[i] = hpack(a[2 * i] * scale, a[2 * i + 1] * scale);
#pragma unroll
    for (int i = 0; i < 3; ++i)
      *(u4v*)(&T[v][l8 * 24 + i * 8]) = u4v{o[4 * i], o[4 * i + 1], o[4 * i + 2], o[4 * i + 3]};
    __syncthreads();
    short* dst = wsc + (size_t)s * 6144;
#pragma unroll
    for (int k = 0; k < 3; ++k) {
      const int unit = t * 3 + k;
      const int F = unit >> 6, lane = unit & 63;
      const int n = F * 16 + (lane & 15);
      const int vr = (lane >> 4) * 8;
      short oo[8];
#pragma unroll
      for (int j = 0; j < 8; ++j) oo[j] = (short)T[vr + j][n];
      *(h8v*)(dst + F * 512 + lane * 8) = *(h8v*)oo;
    }
  } else {
    const int s = bi - 416;
    if (s < 256) {
      const int k32 = t >> 3, l8 = t & 7;
      const float* p = w011 + ((size_t)(s * 32 + k32)) * 64 + l8 * 8;
      f4v x0_ = *(const f4v*)p, x1_ = *(const f4v*)(p + 4);
      u4v o{hpack(x0_.x * sv, x0_.y * sv), hpack(x0_.z * sv, x0_.w * sv),
            hpack(x1_.x * sv, x1_.y * sv), hpack(x1_.z * sv, x1_.w * sv)};
      *(u4v*)(&T[k32][l8 * 8]) = o;
    } else {
      const int sp = s - 256;
      const int blk = sp >> 5, ik = sp & 31;
      const int bu = tab2(PK_BU2, blk), bv = tab2(PK_BV2, blk);
      const int u = bu * 32 + ik;
      const int v = t >> 3, l8 = t & 7;
      float a[8];
      const float* pA = w111 + ((size_t)(u * 64) + bv * 32 + v) * 64 + l8 * 8;
      f4v x0_ = *(const f4v*)pA, x1_ = *(const f4v*)(pA + 4);
      a[0] = x0_.x; a[1] = x0_.y; a[2] = x0_.z; a[3] = x0_.w;
      a[4] = x1_.x; a[5] = x1_.y; a[6] = x1_.z; a[7] = x1_.w;
      if (bu != bv) {
        const float* pB = w111 + ((size_t)((bv * 32 + v)) * 64 + u) * 64 + l8 * 8;
        f4v y0 = *(const f4v*)pB, y1 = *(const f4v*)(pB + 4);
        a[0] -= y0.x; a[1] -= y0.y; a[2] -= y0.z; a[3] -= y0.w;
        a[4] -= y1.x; a[5] -= y1.y; a[6] -= y1.z; a[7] -= y1.w;
      }
      u4v o{hpack(a[0] * sv, a[1] * sv), hpack(a[2] * sv, a[3] * sv),
            hpack(a[4] * sv, a[5] * sv), hpack(a[6] * sv, a[7] * sv)};
      *(u4v*)(&T[v][l8 * 8]) = o;
    }
    __syncthreads();
    const int nf = t >> 6, lane = t & 63;
    const int n = nf * 16 + (lane & 15);
    const int vr = (lane >> 4) * 8;
    short oo[8];
#pragma unroll
    for (int j = 0; j < 8; ++j) oo[j] = (short)T[vr + j][n];
    *(h8v*)(wve + (size_t)s * 2048 + nf * 512 + lane * 8) = *(h8v*)oo;
  }
}

// ---------------- LDS staging: 64 rows of x, f16, 512 threads (2 passes) ----------------
#define X0H_STRIDE 136
#define X1_STRIDE  200

DI void stage_x64w(const float* __restrict__ x, int b0,
                   unsigned short* X0H, unsigned short* X1) {
  const int t = threadIdx.x;            // 512 threads
#pragma unroll
  for (int pass = 0; pass < 2; ++pass) {
    const int row = pass * 32 + (t >> 4), l16 = t & 15;
    const float* src = x + (size_t)(b0 + row) * 320;
    f4v v0 = *(const f4v*)(src + l16 * 8);
    f4v v1 = *(const f4v*)(src + l16 * 8 + 4);
    u4v o{hpack(v0.x, v0.y), hpack(v0.z, v0.w), hpack(v1.x, v1.y), hpack(v1.z, v1.w)};
    *(u4v*)(&X0H[row * X0H_STRIDE + l16 * 8]) = o;
    float buf[12];
    f4v a0 = *(const f4v*)(src + 128 + l16 * 12);
    f4v a1 = *(const f4v*)(src + 128 + l16 * 12 + 4);
    f4v a2 = *(const f4v*)(src + 128 + l16 * 12 + 8);
    buf[0] = a0.x; buf[1] = a0.y; buf[2] = a0.z; buf[3] = a0.w;
    buf[4] = a1.x; buf[5] = a1.y; buf[6] = a1.z; buf[7] = a1.w;
    buf[8] = a2.x; buf[9] = a2.y; buf[10] = a2.z; buf[11] = a2.w;
#pragma unroll
    for (int i = 0; i < 3; ++i) {
      u2v w2{hpack(buf[i], buf[3 + i]), hpack(buf[6 + i], buf[9 + i])};
      *(u2v*)(&X1[row * X1_STRIDE + i * 64 + l16 * 4]) = w2;
    }
  }
}

DI void loadB6(h8v* dst, const short* __restrict__ p) {
#pragma unroll
  for (int nf = 0; nf < 6; ++nf) dst[nf] = *(const h8v*)(p + nf * 512);
}
DI void loadB2(h8v* dst, const short* __restrict__ p) {
  dst[0] = *(const h8v*)p;
  dst[1] = *(const h8v*)(p + 512);
}

// ---------------- split-K GEMM: 64-row tiles x kb2, partials out ----------------
// R13: per-CU weight delivery has been invariant at ~32 B/cy across R8-R12;
// this kernel halves per-CU weight bytes. Grid 256 = 128 tiles(64 rows) x 2 kb,
// kb XCD-affine (xcd 0-3 -> kb0, 4-7 -> kb1): per-XCD working set 3.28 MB fits
// the 4 MB L2. 8 waves = path2 x nh2 x mr2; mr-paired waves read IDENTICAL
// B-streams (L1 sharing). Loop bodies = R9's proven depth-3 register rings
// (kh -> kb, now block-uniform). Each wave owns its output exclusively ->
// NO intra-block reduce, plain f32 partial stores; reduce+epilogue kernel sums.
__global__ __launch_bounds__(512, 2)
void gemm_split(const float* __restrict__ x, const short* __restrict__ wsc,
                const short* __restrict__ wve,
                float* __restrict__ Psc, float* __restrict__ Pve) {
  __shared__ unsigned short X0H[64 * X0H_STRIDE];   // 17408 B
  __shared__ unsigned short X1[64 * X1_STRIDE];     // 25600 B (total 43008)
  const int xcd = blockIdx.x & 7;
  const int kb  = xcd >> 2;                         // XCD-affine K-half
  const int tile = (blockIdx.x >> 3) * 4 + (xcd & 3);  // 0..127, bijective
  const int b0 = tile * 64;

  stage_x64w(x, b0, X0H, X1);
  __syncthreads();

  const int t0 = threadIdx.x;
  const int w = t0 >> 6, lane = t0 & 63;   // w in 0..7
  const bool isvec = w >= 4;
  const int nh = w & 1, mr = (w >> 1) & 1;
  const int q = lane >> 4, r = lane & 15, q8 = q * 8;

  f4v acc[12];
#pragma unroll
  for (int i = 0; i < 12; ++i) acc[i] = f4v{0.f, 0.f, 0.f, 0.f};

  if (!isvec) {
    // ================= scalar path =================
    const unsigned short* x0f[2];
    const unsigned short* x1f[2];
#pragma unroll
    for (int f = 0; f < 2; ++f) {
      x0f[f] = &X0H[(mr * 32 + f * 16 + r) * X0H_STRIDE];
      x1f[f] = &X1[(mr * 32 + f * 16 + r) * X1_STRIDE];
    }

    // ---- region 1: x0 pair blocks, 160 steps (K-half kb), depth-3 ----
    {
      const int s0 = kb * 160;
      const short* wp = wsc + ((size_t)s0 * 12 + nh * 6) * 512 + lane * 8;
      u4v pv[2]; pv[0] = u4v{0, 0, 0, 0}; pv[1] = u4v{0, 0, 0, 0};
      int bu32 = 0;
      h8v b[4][6];
      loadB6(b[0], wp); loadB6(b[1], wp + 6144); loadB6(b[2], wp + 12288);
      for (int t4 = 0; t4 < 40; ++t4) {
#pragma unroll
        for (int uu = 0; uu < 4; ++uu) {
          const int t = t4 * 4 + uu;
          if (t < 157) loadB6(b[(uu + 3) & 3], wp + (size_t)(t + 3) * 6144);
          const int s = s0 + t;
          const int ik = s & 31;
          if (t == 0 || ik == 0) {      // new 32x32 block (block-uniform)
            const int blk = s >> 5;
            const int bv32 = tab2(PK_BV0, blk) * 32;
            bu32 = tab2(PK_BU0, blk) * 32;
            pv[0] = *(const u4v*)(x0f[0] + bv32 + q8);
            pv[1] = *(const u4v*)(x0f[1] + bv32 + q8);
          }
          h8v a[2];
#pragma unroll
          for (int f = 0; f < 2; ++f) {
            h2v xu = hsplat(x0f[f][bu32 + ik]);
            u4v pa;
#pragma unroll
            for (int m = 0; m < 4; ++m) pa[m] = hu(uh(pv[f][m]) * xu);
            a[f] = __builtin_bit_cast(h8v, pa);
          }
          __builtin_amdgcn_s_setprio(1);
#pragma unroll
          for (int nf = 0; nf < 6; ++nf)
#pragma unroll
            for (int f = 0; f < 2; ++f)
              acc[f * 6 + nf] = mfma16h(a[f], b[uu & 3][nf], acc[f * 6 + nf]);
          __builtin_amdgcn_s_setprio(0);
        }
      }
    }

    // ---- region 2: x1-dots pair blocks, 48 steps (K-half kb) ----
    {
      const int sp0 = kb * 48;
      const short* wp = wsc + ((size_t)(320 + sp0) * 12 + nh * 6) * 512 + lane * 8;
      h8v b[4][6];
      loadB6(b[0], wp); loadB6(b[1], wp + 6144); loadB6(b[2], wp + 12288);
      for (int t4 = 0; t4 < 12; ++t4) {
#pragma unroll
        for (int uu = 0; uu < 4; ++uu) {
          const int t = t4 * 4 + uu;
          if (t < 45) loadB6(b[(uu + 3) & 3], wp + (size_t)(t + 3) * 6144);
          const int sp = sp0 + t;
          const int blk = sp >> 5, ik = sp & 31;
          const int bu32 = tab2(PK_BU2, blk) * 32;
          const int bv32 = tab2(PK_BV2, blk) * 32;
          h8v a[2];
#pragma unroll
          for (int f = 0; f < 2; ++f) {
            h2v us0 = hsplat(x1f[f][bu32 + ik]);
            h2v us1 = hsplat(x1f[f][64 + bu32 + ik]);
            h2v us2 = hsplat(x1f[f][128 + bu32 + ik]);
            u4v p0 = *(const u4v*)(x1f[f] + bv32 + q8);
            u4v p1 = *(const u4v*)(x1f[f] + 64 + bv32 + q8);
            u4v p2 = *(const u4v*)(x1f[f] + 128 + bv32 + q8);
            u4v pa;
#pragma unroll
            for (int m = 0; m < 4; ++m) {
              h2v sm = uh(p0[m]) * us0;
              sm = sm + uh(p1[m]) * us1;
              sm = sm + uh(p2[m]) * us2;
              pa[m] = hu(sm);
            }
            a[f] = __builtin_bit_cast(h8v, pa);
          }
          __builtin_amdgcn_s_setprio(1);
#pragma unroll
          for (int nf = 0; nf < 6; ++nf)
#pragma unroll
            for (int f = 0; f < 2; ++f)
              acc[f * 6 + nf] = mfma16h(a[f], b[uu & 3][nf], acc[f * 6 + nf]);
          __builtin_amdgcn_s_setprio(0);
        }
      }
    }

    // ---- plain f32 partial store (exclusive ownership) ----
#pragma unroll
    for (int f = 0; f < 2; ++f)
#pragma unroll
      for (int nf = 0; nf < 6; ++nf) {
        const int n = (nh * 6 + nf) * 16 + r;
#pragma unroll
        for (int reg = 0; reg < 4; ++reg) {
          const int row = b0 + mr * 32 + f * 16 + q * 4 + reg;
          Psc[((size_t)kb * B_ + row) * NW_ + n] = acc[f * 6 + nf][reg];
        }
      }
  } else {
    // ================= vector path =================
    const unsigned short* x0r[2];
    const unsigned short* x1r[2];
#pragma unroll
    for (int ff = 0; ff < 2; ++ff) {
      x0r[ff] = &X0H[(mr * 32 + ff * 16 + r) * X0H_STRIDE];
      x1r[ff] = &X1[(mr * 32 + ff * 16 + r) * X1_STRIDE];
    }

    // ---- region 1: v011, 128 steps (u in [kb*64,+64), j in {0,1}), depth-3 ----
    {
      const int u0 = kb * 64;
      const short* wp = wve + (size_t)(u0 * 2) * 2048 + nh * 1024 + lane * 8;
      h8v b[4][2];
      loadB2(b[0], wp); loadB2(b[1], wp + 2048); loadB2(b[2], wp + 4096);
      for (int t4 = 0; t4 < 32; ++t4) {
#pragma unroll
        for (int uu = 0; uu < 4; ++uu) {
          const int t = t4 * 4 + uu;
          if (t < 125) loadB2(b[(uu + 3) & 3], wp + (size_t)(t + 3) * 2048);
          const int g = t >> 1, j = t & 1;
          const int vb = j * 32 + q8;
          h8v a[2][3];
#pragma unroll
          for (int ff = 0; ff < 2; ++ff) {
            h2v xu2 = hsplat(x0r[ff][u0 + g]);
#pragma unroll
            for (int i = 0; i < 3; ++i) {
              u4v p = *(const u4v*)(x1r[ff] + i * 64 + vb);
              u4v pa;
#pragma unroll
              for (int m = 0; m < 4; ++m) pa[m] = hu(uh(p[m]) * xu2);
              a[ff][i] = __builtin_bit_cast(h8v, pa);
            }
          }
          __builtin_amdgcn_s_setprio(1);
#pragma unroll
          for (int ip = 0; ip < 3; ++ip)
#pragma unroll
            for (int nfl = 0; nfl < 2; ++nfl)
#pragma unroll
              for (int ff = 0; ff < 2; ++ff)
                acc[(ff * 3 + ip) * 2 + nfl] =
                    mfma16h(a[ff][ip], b[uu & 3][nfl], acc[(ff * 3 + ip) * 2 + nfl]);
          __builtin_amdgcn_s_setprio(0);
        }
      }
    }

    // ---- region 2: v111 antisym, 48 steps (sp in [kb*48,+48)) ----
    {
      const int sp0 = kb * 48;
      const short* wp = wve + (size_t)(256 + sp0) * 2048 + nh * 1024 + lane * 8;
      h8v b[4][2];
      loadB2(b[0], wp); loadB2(b[1], wp + 2048); loadB2(b[2], wp + 4096);
      for (int t4 = 0; t4 < 12; ++t4) {
#pragma unroll
        for (int uu = 0; uu < 4; ++uu) {
          const int t = t4 * 4 + uu;
          if (t < 45) loadB2(b[(uu + 3) & 3], wp + (size_t)(t + 3) * 2048);
          const int sp = sp0 + t;
          const int blk = sp >> 5, ik = sp & 31;
          const int bu32 = tab2(PK_BU2, blk) * 32;
          const int bv32 = tab2(PK_BV2, blk) * 32;
          h8v a[2][3];
#pragma unroll
          for (int ff = 0; ff < 2; ++ff) {
            h2v us[3];
            u4v p[3];
#pragma unroll
            for (int i = 0; i < 3; ++i) {
              us[i] = hsplat(x1r[ff][i * 64 + bu32 + ik]);
              p[i] = *(const u4v*)(x1r[ff] + i * 64 + bv32 + q8);
            }
#pragma unroll
            for (int ip = 0; ip < 3; ++ip) {
              const int i1 = (ip + 1) % 3, i2 = (ip + 2) % 3;
              u4v pa;
#pragma unroll
              for (int m = 0; m < 4; ++m)
                pa[m] = hu(uh(p[i2][m]) * us[i1] - uh(p[i1][m]) * us[i2]);
              a[ff][ip] = __builtin_bit_cast(h8v, pa);
            }
          }
          __builtin_amdgcn_s_setprio(1);
#pragma unroll
          for (int ip = 0; ip < 3; ++ip)
#pragma unroll
            for (int nfl = 0; nfl < 2; ++nfl)
#pragma unroll
              for (int ff = 0; ff < 2; ++ff)
                acc[(ff * 3 + ip) * 2 + nfl] =
                    mfma16h(a[ff][ip], b[uu & 3][nfl], acc[(ff * 3 + ip) * 2 + nfl]);
          __builtin_amdgcn_s_setprio(0);
        }
      }
    }

    // ---- plain f32 partial store ----
#pragma unroll
    for (int ff = 0; ff < 2; ++ff)
#pragma unroll
      for (int ip = 0; ip < 3; ++ip)
#pragma unroll
        for (int nfl = 0; nfl < 2; ++nfl) {
          const int ai = (ff * 3 + ip) * 2 + nfl;
          const int n = (nh * 2 + nfl) * 16 + r;
#pragma unroll
          for (int reg = 0; reg < 4; ++reg) {
            const int row = b0 + mr * 32 + ff * 16 + q * 4 + reg;
            Pve[(((size_t)kb * 3 + ip) * B_ + row) * 64 + n] = acc[ai][reg];
          }
        }
  }
}

// ---------------- reduce + epilogue: sum kb partials, silu/gate, interleave ----------------
__global__ void reduce_ep(const float* __restrict__ Psc, const float* __restrict__ Pve,
                          float* __restrict__ out) {
  int t = blockIdx.x * blockDim.x + threadIdx.x;  // B*192 threads exactly
  int b = t / NW_, c = t % NW_;
  float v = Psc[(size_t)b * NW_ + c] + Psc[(size_t)(B_ + b) * NW_ + c];
  float sg = 1.0f / (1.0f + __expf(-v));
  if (c < 128) {
    out[(size_t)b * 320 + c] = v * sg;            // silu
  } else {
    int w = c - 128;
#pragma unroll
    for (int i = 0; i < 3; ++i) {
      float vv = Pve[((size_t)i * B_ + b) * 64 + w] +
                 Pve[((size_t)(3 + i) * B_ + b) * 64 + w];
      out[(size_t)b * 320 + 128 + w * 3 + i] = vv * sg;
    }
  }
}

// ---------------- launch ----------------
extern "C" void kernel_launch(void* const* d_in, const int* in_sizes, int n_in,
                              void* d_out, int out_size, void* d_ws, size_t ws_size,
                              hipStream_t stream) {
  const float* x    = (const float*)d_in[0];
  const float* w000 = (const float*)d_in[1];
  const float* w110 = (const float*)d_in[2];
  const float* w011 = (const float*)d_in[3];
  const float* w111 = (const float*)d_in[4];
  float* out = (float*)d_out;

  char* ws = (char*)d_ws;
  short* wsc = (short*)ws;                        // 416*6144*2 = 5,111,808 B
  short* wve = (short*)(ws + 5111808);            // 352*2048*2 = 1,441,792 B
  float* Psc = (float*)(ws + 6553600);            // 2*8192*192*4 = 12,582,912 B
  float* Pve = (float*)(ws + 19136512);           // 2*3*8192*64*4 = 12,582,912 B
  // total ws use: 31,719,424 B

  prep_all  <<<768, 256, 0, stream>>>(w000, w110, w011, w111, wsc, wve);
  gemm_split<<<256, 512, 0, stream>>>(x, wsc, wve, Psc, Pve);
  reduce_ep <<<6144, 256, 0, stream>>>(Psc, Pve, out);
}